// Round 7
// baseline (212.973 us; speedup 1.0000x reference)
//
#include <hip/hip_runtime.h>
#include <hip/hip_bf16.h>

typedef __bf16 bf16x8 __attribute__((ext_vector_type(8)));
typedef float  f32x4  __attribute__((ext_vector_type(4)));
typedef short  short8 __attribute__((ext_vector_type(8)));

#define KDE_IGNORE (-100)
#define NSL  16       // N slices (2 per XCD)
#define GBM  64       // m rows per block
#define GBN  64       // n cols per n-tile
#define BK   128      // k per phase (2 phases over K=256)
#define GD   256
#define NSLOT (NSL * 2)

__device__ __forceinline__ f32x4 mfma16x16(bf16x8 a, bf16x8 b, f32x4 c) {
  return __builtin_amdgcn_mfma_f32_16x16x32_bf16(a, b, c, 0, 0, 0);
}

// ---- Kernel 1: supp row norms only (fp32, exact).
__global__ void supp_prep_kernel(const float* __restrict__ supp, float* __restrict__ sn, int N) {
  int row = blockIdx.x * 8 + ((threadIdx.x >> 6) << 1) + ((threadIdx.x & 63) >> 5);
  int c = threadIdx.x & 31;
  const float* src = supp + (size_t)row * GD + c * 8;
  float4 a = *reinterpret_cast<const float4*>(src);
  float4 b = *reinterpret_cast<const float4*>(src + 4);
  float s = a.x*a.x + a.y*a.y + a.z*a.z + a.w*a.w
          + b.x*b.x + b.y*b.y + b.z*b.z + b.w*b.w;
#pragma unroll
  for (int off = 16; off >= 1; off >>= 1) s += __shfl_xor(s, off, 32);
  if (c == 0) sn[row] = s;
}

// convert 8 fp32 -> 8 bf16 (as bf16x8 for MFMA operands)
__device__ __forceinline__ bf16x8 cvt8b(const float* p) {
  float4 a = *reinterpret_cast<const float4*>(p);
  float4 b = *reinterpret_cast<const float4*>(p + 4);
  union { bf16x8 v; __bf16 h[8]; } u;
  u.h[0] = (__bf16)a.x; u.h[1] = (__bf16)a.y; u.h[2] = (__bf16)a.z; u.h[3] = (__bf16)a.w;
  u.h[4] = (__bf16)b.x; u.h[5] = (__bf16)b.y; u.h[6] = (__bf16)b.z; u.h[7] = (__bf16)b.w;
  return u.v;
}

// same but as short8 (for LDS stores)
__device__ __forceinline__ short8 cvt8s(const float* p) {
  union { bf16x8 b; short8 s; } u;
  u.b = cvt8b(p);
  return u.s;
}

// ---- Kernel 2: fused GEMM + exp + masked row-accumulate, atomic-free.
// 256 thr = 4 waves (2m x 2n); block tile 64m x 64n per n-tile, K phased 2x128.
// A (pred) full-K in registers; B double-buffered in LDS (2 x 16KB).
// Grid = (M/64)*16 = 1024 blocks -> 4 blocks/CU, 16 waves/CU, 4 waves/SIMD.
__global__ __launch_bounds__(256, 4)
void kde_gemm_kernel(const float* __restrict__ pred, const float* __restrict__ suppF,
                     const int* __restrict__ tgt, const int* __restrict__ suppT,
                     const float* __restrict__ sn,
                     float* __restrict__ denomP, float* __restrict__ numerP,
                     int M, int N) {
  __shared__ __align__(16) short Bs[2][GBN * BK];   // 2 x 16 KiB

  const int bid = blockIdx.x;
  const int mb  = bid >> 4;           // 0..M/64-1
  const int s   = bid & 15;           // slice; XCD = s & 7 (16 | 8)
  const int m0  = mb * GBM;
  const int nslice = N >> 4;          // 1024
  const int nbase  = s * nslice;
  const int nphase = (nslice / GBN) * 2;   // 32 phases (16 n-tiles x 2)
  const int t    = threadIdx.x;
  const int lane = t & 63;
  const int wid  = t >> 6;            // 0..3
  const int wm   = (wid >> 1) * 32;
  const int wng  = wid & 1;
  const int wnl  = wng * 32;
  const int lr = lane >> 4, lc = lane & 15;

  // ---- A fragments: full K=256 in registers (bf16), converted once.
  bf16x8 af[2][8];
#pragma unroll
  for (int mt = 0; mt < 2; ++mt) {
    const float* base = pred + (size_t)(m0 + wm + mt * 16 + lc) * GD + lr * 8;
#pragma unroll
    for (int kk = 0; kk < 8; ++kk) af[mt][kk] = cvt8b(base + kk * 32);
  }
  int tmv[2][4];
#pragma unroll
  for (int mt = 0; mt < 2; ++mt)
#pragma unroll
    for (int rg = 0; rg < 4; ++rg)
      tmv[mt][rg] = tgt[m0 + wm + mt * 16 + lr * 4 + rg];

  float dac[2][4] = {}, nac[2][4] = {};

  const float SC  = 1.4426950408889634f / 128.0f;   // log2e/128 (for 2*dot)
  const float SCH = 1.4426950408889634f / 256.0f;   // log2e/256 (for sn)

  // staging geometry: 16KB phase tile = 64 rows x 16 chunks(16B); 4 chunks/thread
  // chunk indices for this thread: C = i*256+t -> row=C>>4, j=C&15
  // ---- stage phase 0 (n-tile 0, k-half 0) into buffer 0
#pragma unroll
  for (int i = 0; i < 4; ++i) {
    int C = i * 256 + t; int row = C >> 4; int j = C & 15;
    short8 v = cvt8s(suppF + (size_t)(nbase + row) * GD + j * 8);
    *reinterpret_cast<short8*>(&Bs[0][row * BK + ((j ^ (row & 15)) << 3)]) = v;
  }
  __syncthreads();

  f32x4 acc[2][2] = {};
  float snv[2]; int stv[2];
#pragma unroll
  for (int nt = 0; nt < 2; ++nt) {
    int j = nbase + wnl + nt * 16 + lc;
    snv[nt] = sn[j]; stv[nt] = suppT[j];
  }

  int cur = 0;
  for (int ph = 0; ph < nphase; ++ph) {
    const int p = ph & 1;               // k-half of current phase
    const bool more = (ph + 1 < nphase);

    // T14: issue+convert next phase's 16KB early (latency under MFMA)
    short8 sreg[4];
    if (more) {
      const int nt2 = (ph + 1) >> 1, p2 = (ph + 1) & 1;
      const int nr0 = nbase + nt2 * GBN;
      const int ko  = p2 * BK;
#pragma unroll
      for (int i = 0; i < 4; ++i) {
        int C = i * 256 + t; int row = C >> 4; int j = C & 15;
        sreg[i] = cvt8s(suppF + (size_t)(nr0 + row) * GD + ko + j * 8);
      }
    }

    // MFMA: 16 per wave (2m x 2n x 4k-slices of 32)
    __builtin_amdgcn_s_setprio(1);
#pragma unroll
    for (int ks = 0; ks < 4; ++ks) {
      bf16x8 bfr[2];
#pragma unroll
      for (int nt = 0; nt < 2; ++nt) {
        int r = wnl + nt * 16 + lc;
        int cs = (ks * 4 + lr) ^ (r & 15);
        bfr[nt] = *reinterpret_cast<const bf16x8*>(&Bs[cur][r * BK + (cs << 3)]);
      }
#pragma unroll
      for (int mt = 0; mt < 2; ++mt)
#pragma unroll
        for (int nt = 0; nt < 2; ++nt)
          acc[mt][nt] = mfma16x16(af[mt][p * 4 + ks], bfr[nt], acc[mt][nt]);
    }
    __builtin_amdgcn_s_setprio(0);

    // write-late: staged regs -> other buffer (its readers finished at ph-1's barrier)
    if (more) {
#pragma unroll
      for (int i = 0; i < 4; ++i) {
        int C = i * 256 + t; int row = C >> 4; int j = C & 15;
        *reinterpret_cast<short8*>(&Bs[cur ^ 1][row * BK + ((j ^ (row & 15)) << 3)]) = sreg[i];
      }
    }

    // n-tile complete at odd phase: fused epilogue, then reset acc + metadata
    if (p == 1) {
#pragma unroll
      for (int nt = 0; nt < 2; ++nt) {
        float sh = -snv[nt] * SCH;
#pragma unroll
        for (int mt = 0; mt < 2; ++mt)
#pragma unroll
          for (int rg = 0; rg < 4; ++rg) {
            float e = exp2f(fmaf(acc[mt][nt][rg], SC, sh));
            dac[mt][rg] += e;
            nac[mt][rg] += (stv[nt] == tmv[mt][rg]) ? e : 0.0f;
          }
      }
#pragma unroll
      for (int mt = 0; mt < 2; ++mt)
#pragma unroll
        for (int nt = 0; nt < 2; ++nt) acc[mt][nt] = f32x4{0.f, 0.f, 0.f, 0.f};
      if (more) {
        const int nn0 = nbase + ((ph + 1) >> 1) * GBN;
#pragma unroll
        for (int nt = 0; nt < 2; ++nt) {
          int j = nn0 + wnl + nt * 16 + lc;
          snv[nt] = sn[j]; stv[nt] = suppT[j];
        }
      }
    }
    __syncthreads();
    cur ^= 1;
  }

  // reduce over the 16 lanes (lc) sharing each m, write slot partials
#pragma unroll
  for (int off = 1; off < 16; off <<= 1) {
#pragma unroll
    for (int mt = 0; mt < 2; ++mt)
#pragma unroll
      for (int rg = 0; rg < 4; ++rg) {
        dac[mt][rg] += __shfl_xor(dac[mt][rg], off);
        nac[mt][rg] += __shfl_xor(nac[mt][rg], off);
      }
  }
  if (lc == 0) {
    const int slot = s * 2 + wng;           // 32 slots per m
#pragma unroll
    for (int mt = 0; mt < 2; ++mt)
#pragma unroll
      for (int rg = 0; rg < 4; ++rg) {
        int m = m0 + wm + mt * 16 + lr * 4 + rg;
        denomP[(size_t)slot * M + m] = dac[mt][rg];
        numerP[(size_t)slot * M + m] = nac[mt][rg];
      }
  }
}

// ---- Kernel 3: per-m sum over 32 slots -> nll, per-block partial sums
__global__ void kde_reduce_kernel(const float* __restrict__ denomP, const float* __restrict__ numerP,
                                  const int* __restrict__ tgt,
                                  float* __restrict__ bsum, float* __restrict__ bcnt, int M) {
  __shared__ float sS[4], sC[4];
  int m = blockIdx.x * 256 + threadIdx.x;
  float den = 0.0f, num = 0.0f;
#pragma unroll
  for (int sl = 0; sl < NSLOT; ++sl) {
    den += denomP[(size_t)sl * M + m];
    num += numerP[(size_t)sl * M + m];
  }
  int tg = tgt[m];
  bool valid = (tg != KDE_IGNORE);
  float p = fmaxf(num / fmaxf(den, 1e-10f), 1e-10f);
  float nll = valid ? -logf(p) : 0.0f;
  float cnt = valid ? 1.0f : 0.0f;
#pragma unroll
  for (int off = 32; off >= 1; off >>= 1) {
    nll += __shfl_xor(nll, off);
    cnt += __shfl_xor(cnt, off);
  }
  int wid = threadIdx.x >> 6, lane = threadIdx.x & 63;
  if (lane == 0) { sS[wid] = nll; sC[wid] = cnt; }
  __syncthreads();
  if (threadIdx.x == 0) {
    bsum[blockIdx.x] = sS[0] + sS[1] + sS[2] + sS[3];
    bcnt[blockIdx.x] = sC[0] + sC[1] + sC[2] + sC[3];
  }
}

__global__ void kde_final_kernel(const float* __restrict__ bsum, const float* __restrict__ bcnt,
                                 float* __restrict__ out, int nb) {
  int tid = threadIdx.x;
  float s = (tid < nb) ? bsum[tid] : 0.0f;
  float c = (tid < nb) ? bcnt[tid] : 0.0f;
#pragma unroll
  for (int off = 32; off >= 1; off >>= 1) {
    s += __shfl_xor(s, off);
    c += __shfl_xor(c, off);
  }
  if (tid == 0) out[0] = s / fmaxf(c, 1.0f);
}

extern "C" void kernel_launch(void* const* d_in, const int* in_sizes, int n_in,
                              void* d_out, int out_size, void* d_ws, size_t ws_size,
                              hipStream_t stream) {
  const float* supp  = (const float*)d_in[0];   // (N, 256)
  const float* pred  = (const float*)d_in[1];   // (M, 256)
  const int*   suppT = (const int*)d_in[2];     // (N,)
  const int*   tgt   = (const int*)d_in[3];     // (M,)
  const int N = in_sizes[2];
  const int M = in_sizes[3];

  float* sn     = (float*)d_ws;                      // N
  float* denomP = sn + N;                            // NSLOT*M
  float* numerP = denomP + (size_t)NSLOT * M;        // NSLOT*M
  float* bsum   = numerP + (size_t)NSLOT * M;        // M/256
  float* bcnt   = bsum + 16;                         // M/256

  supp_prep_kernel<<<dim3(N / 8), dim3(256), 0, stream>>>(supp, sn, N);

  dim3 grid((M / GBM) * NSL);   // 1024 blocks; XCD = slice & 7
  kde_gemm_kernel<<<grid, dim3(256), 0, stream>>>(
      pred, supp, tgt, suppT, sn, denomP, numerP, M, N);

  kde_reduce_kernel<<<dim3(M / 256), dim3(256), 0, stream>>>(denomP, numerP, tgt, bsum, bcnt, M);
  kde_final_kernel<<<dim3(1), dim3(64), 0, stream>>>(bsum, bcnt, (float*)d_out, M / 256);
}

// Round 8
// 185.248 us; speedup vs baseline: 1.1497x; 1.1497x over previous
//
#include <hip/hip_runtime.h>
#include <hip/hip_bf16.h>

typedef __bf16 bf16x8 __attribute__((ext_vector_type(8)));
typedef float  f32x4  __attribute__((ext_vector_type(4)));
typedef short  short8 __attribute__((ext_vector_type(8)));

#define KDE_IGNORE (-100)
#define NSL  16       // N slices (2 per XCD)
#define GBM  64       // m rows per block
#define GBN  64       // n cols per n-tile
#define BK   128      // k per phase (2 phases over K=256)
#define GD   256
#define NSLOT (NSL * 2)

__device__ __forceinline__ f32x4 mfma16x16(bf16x8 a, bf16x8 b, f32x4 c) {
  return __builtin_amdgcn_mfma_f32_16x16x32_bf16(a, b, c, 0, 0, 0);
}

// ---- Kernel 1: supp row norms only (fp32, exact).
__global__ void supp_prep_kernel(const float* __restrict__ supp, float* __restrict__ sn, int N) {
  int row = blockIdx.x * 8 + ((threadIdx.x >> 6) << 1) + ((threadIdx.x & 63) >> 5);
  int c = threadIdx.x & 31;
  const float* src = supp + (size_t)row * GD + c * 8;
  float4 a = *reinterpret_cast<const float4*>(src);
  float4 b = *reinterpret_cast<const float4*>(src + 4);
  float s = a.x*a.x + a.y*a.y + a.z*a.z + a.w*a.w
          + b.x*b.x + b.y*b.y + b.z*b.z + b.w*b.w;
#pragma unroll
  for (int off = 16; off >= 1; off >>= 1) s += __shfl_xor(s, off, 32);
  if (c == 0) sn[row] = s;
}

// convert 8 fp32 -> 8 bf16 (as bf16x8 for MFMA operands)
__device__ __forceinline__ bf16x8 cvt8b(const float* p) {
  float4 a = *reinterpret_cast<const float4*>(p);
  float4 b = *reinterpret_cast<const float4*>(p + 4);
  union { bf16x8 v; __bf16 h[8]; } u;
  u.h[0] = (__bf16)a.x; u.h[1] = (__bf16)a.y; u.h[2] = (__bf16)a.z; u.h[3] = (__bf16)a.w;
  u.h[4] = (__bf16)b.x; u.h[5] = (__bf16)b.y; u.h[6] = (__bf16)b.z; u.h[7] = (__bf16)b.w;
  return u.v;
}

// same but as short8 (for LDS stores)
__device__ __forceinline__ short8 cvt8s(const float* p) {
  union { bf16x8 b; short8 s; } u;
  u.b = cvt8b(p);
  return u.s;
}

// ---- Kernel 2: fused GEMM + exp + masked row-accumulate, atomic-free.
// 256 thr = 4 waves (2m x 2n); block tile 64m x 64n per n-tile, K phased 2x128.
// A (pred) full-K in registers (ALL indices compile-time -> stays in VGPRs);
// B double-buffered in LDS (2 x 16KB), one barrier per phase.
// Grid = (M/64)*16 = 1024 blocks -> 4 blocks/CU, 16 waves/CU, 4 waves/SIMD.
__global__ __launch_bounds__(256, 4)
void kde_gemm_kernel(const float* __restrict__ pred, const float* __restrict__ suppF,
                     const int* __restrict__ tgt, const int* __restrict__ suppT,
                     const float* __restrict__ sn,
                     float* __restrict__ denomP, float* __restrict__ numerP,
                     int M, int N) {
  __shared__ __align__(16) short Bs[2][GBN * BK];   // 2 x 16 KiB

  const int bid = blockIdx.x;
  const int mb  = bid >> 4;           // 0..M/64-1
  const int s   = bid & 15;           // slice; XCD = s & 7
  const int m0  = mb * GBM;
  const int nslice = N >> 4;          // 1024
  const int nbase  = s * nslice;
  const int ntile  = nslice / GBN;    // 16 n-tiles (2 phases each)
  const int t    = threadIdx.x;
  const int lane = t & 63;
  const int wid  = t >> 6;            // 0..3
  const int wm   = (wid >> 1) * 32;
  const int wng  = wid & 1;
  const int wnl  = wng * 32;
  const int lr = lane >> 4, lc = lane & 15;

  // ---- A fragments: full K=256 in registers (bf16), converted once.
  bf16x8 af[2][8];
#pragma unroll
  for (int mt = 0; mt < 2; ++mt) {
    const float* base = pred + (size_t)(m0 + wm + mt * 16 + lc) * GD + lr * 8;
#pragma unroll
    for (int kk = 0; kk < 8; ++kk) af[mt][kk] = cvt8b(base + kk * 32);
  }
  int tmv[2][4];
#pragma unroll
  for (int mt = 0; mt < 2; ++mt)
#pragma unroll
    for (int rg = 0; rg < 4; ++rg)
      tmv[mt][rg] = tgt[m0 + wm + mt * 16 + lr * 4 + rg];

  float dac[2][4] = {}, nac[2][4] = {};

  const float SC  = 1.4426950408889634f / 128.0f;   // log2e/128 (for 2*dot)
  const float SCH = 1.4426950408889634f / 256.0f;   // log2e/256 (for sn)

  // staging geometry: 16KB phase tile = 64 rows x 16 chunks(16B); 4 chunks/thread
  // thread's chunks: C = i*256+t -> row=C>>4, j=C&15
  const int srow0 = (0 * 256 + t) >> 4, sj0 = t & 15;          // i=0
  // ---- stage (tile 0, k-half 0) into Bs[0]
#pragma unroll
  for (int i = 0; i < 4; ++i) {
    int C = i * 256 + t; int row = C >> 4; int j = C & 15;
    short8 v = cvt8s(suppF + (size_t)(nbase + row) * GD + j * 8);
    *reinterpret_cast<short8*>(&Bs[0][row * BK + ((j ^ (row & 15)) << 3)]) = v;
  }
  __syncthreads();
  (void)srow0; (void)sj0;

  f32x4 acc[2][2] = {};
  float snv[2]; int stv[2];
#pragma unroll
  for (int nt = 0; nt < 2; ++nt) {
    int j = nbase + wnl + nt * 16 + lc;
    snv[nt] = sn[j]; stv[nt] = suppT[j];
  }

  for (int it = 0; it < ntile; ++it) {
    const int n0 = nbase + it * GBN;
    const bool more = (it + 1 < ntile);

    // ======== phase 0: compute k-half 0 from Bs[0]; stage (it, kh=1) -> Bs[1]
    short8 sreg[4];
#pragma unroll
    for (int i = 0; i < 4; ++i) {
      int C = i * 256 + t; int row = C >> 4; int j = C & 15;
      sreg[i] = cvt8s(suppF + (size_t)(n0 + row) * GD + BK + j * 8);
    }
    __builtin_amdgcn_s_setprio(1);
#pragma unroll
    for (int ks = 0; ks < 4; ++ks) {
      bf16x8 bfr[2];
#pragma unroll
      for (int nt = 0; nt < 2; ++nt) {
        int r = wnl + nt * 16 + lc;
        int cs = (ks * 4 + lr) ^ (r & 15);
        bfr[nt] = *reinterpret_cast<const bf16x8*>(&Bs[0][r * BK + (cs << 3)]);
      }
#pragma unroll
      for (int mt = 0; mt < 2; ++mt)
#pragma unroll
        for (int nt = 0; nt < 2; ++nt)
          acc[mt][nt] = mfma16x16(af[mt][ks], bfr[nt], acc[mt][nt]);
    }
    __builtin_amdgcn_s_setprio(0);
#pragma unroll
    for (int i = 0; i < 4; ++i) {
      int C = i * 256 + t; int row = C >> 4; int j = C & 15;
      *reinterpret_cast<short8*>(&Bs[1][row * BK + ((j ^ (row & 15)) << 3)]) = sreg[i];
    }
    __syncthreads();

    // ======== phase 1: compute k-half 1 from Bs[1]; stage (it+1, kh=0) -> Bs[0]
    if (more) {
#pragma unroll
      for (int i = 0; i < 4; ++i) {
        int C = i * 256 + t; int row = C >> 4; int j = C & 15;
        sreg[i] = cvt8s(suppF + (size_t)(n0 + GBN + row) * GD + j * 8);
      }
    }
    __builtin_amdgcn_s_setprio(1);
#pragma unroll
    for (int ks = 0; ks < 4; ++ks) {
      bf16x8 bfr[2];
#pragma unroll
      for (int nt = 0; nt < 2; ++nt) {
        int r = wnl + nt * 16 + lc;
        int cs = (ks * 4 + lr) ^ (r & 15);
        bfr[nt] = *reinterpret_cast<const bf16x8*>(&Bs[1][r * BK + (cs << 3)]);
      }
#pragma unroll
      for (int mt = 0; mt < 2; ++mt)
#pragma unroll
        for (int nt = 0; nt < 2; ++nt)
          acc[mt][nt] = mfma16x16(af[mt][4 + ks], bfr[nt], acc[mt][nt]);
    }
    __builtin_amdgcn_s_setprio(0);
    if (more) {
#pragma unroll
      for (int i = 0; i < 4; ++i) {
        int C = i * 256 + t; int row = C >> 4; int j = C & 15;
        *reinterpret_cast<short8*>(&Bs[0][row * BK + ((j ^ (row & 15)) << 3)]) = sreg[i];
      }
    }

    // ---- n-tile epilogue: e = 2^((2c - sn)*log2e/256); pn cancels in ratio
#pragma unroll
    for (int nt = 0; nt < 2; ++nt) {
      float sh = -snv[nt] * SCH;
#pragma unroll
      for (int mt = 0; mt < 2; ++mt)
#pragma unroll
        for (int rg = 0; rg < 4; ++rg) {
          float e = exp2f(fmaf(acc[mt][nt][rg], SC, sh));
          dac[mt][rg] += e;
          nac[mt][rg] += (stv[nt] == tmv[mt][rg]) ? e : 0.0f;
        }
    }
#pragma unroll
    for (int mt = 0; mt < 2; ++mt)
#pragma unroll
      for (int nt = 0; nt < 2; ++nt) acc[mt][nt] = f32x4{0.f, 0.f, 0.f, 0.f};
    if (more) {
      const int nn0 = n0 + GBN;
#pragma unroll
      for (int nt = 0; nt < 2; ++nt) {
        int j = nn0 + wnl + nt * 16 + lc;
        snv[nt] = sn[j]; stv[nt] = suppT[j];
      }
    }
    __syncthreads();
  }

  // reduce over the 16 lanes (lc) sharing each m, write slot partials
#pragma unroll
  for (int off = 1; off < 16; off <<= 1) {
#pragma unroll
    for (int mt = 0; mt < 2; ++mt)
#pragma unroll
      for (int rg = 0; rg < 4; ++rg) {
        dac[mt][rg] += __shfl_xor(dac[mt][rg], off);
        nac[mt][rg] += __shfl_xor(nac[mt][rg], off);
      }
  }
  if (lc == 0) {
    const int slot = s * 2 + wng;           // 32 slots per m
#pragma unroll
    for (int mt = 0; mt < 2; ++mt)
#pragma unroll
      for (int rg = 0; rg < 4; ++rg) {
        int m = m0 + wm + mt * 16 + lr * 4 + rg;
        denomP[(size_t)slot * M + m] = dac[mt][rg];
        numerP[(size_t)slot * M + m] = nac[mt][rg];
      }
  }
}

// ---- Kernel 3: per-m sum over 32 slots -> nll, per-block partial sums
__global__ void kde_reduce_kernel(const float* __restrict__ denomP, const float* __restrict__ numerP,
                                  const int* __restrict__ tgt,
                                  float* __restrict__ bsum, float* __restrict__ bcnt, int M) {
  __shared__ float sS[4], sC[4];
  int m = blockIdx.x * 256 + threadIdx.x;
  float den = 0.0f, num = 0.0f;
#pragma unroll
  for (int sl = 0; sl < NSLOT; ++sl) {
    den += denomP[(size_t)sl * M + m];
    num += numerP[(size_t)sl * M + m];
  }
  int tg = tgt[m];
  bool valid = (tg != KDE_IGNORE);
  float p = fmaxf(num / fmaxf(den, 1e-10f), 1e-10f);
  float nll = valid ? -logf(p) : 0.0f;
  float cnt = valid ? 1.0f : 0.0f;
#pragma unroll
  for (int off = 32; off >= 1; off >>= 1) {
    nll += __shfl_xor(nll, off);
    cnt += __shfl_xor(cnt, off);
  }
  int wid = threadIdx.x >> 6, lane = threadIdx.x & 63;
  if (lane == 0) { sS[wid] = nll; sC[wid] = cnt; }
  __syncthreads();
  if (threadIdx.x == 0) {
    bsum[blockIdx.x] = sS[0] + sS[1] + sS[2] + sS[3];
    bcnt[blockIdx.x] = sC[0] + sC[1] + sC[2] + sC[3];
  }
}

__global__ void kde_final_kernel(const float* __restrict__ bsum, const float* __restrict__ bcnt,
                                 float* __restrict__ out, int nb) {
  int tid = threadIdx.x;
  float s = (tid < nb) ? bsum[tid] : 0.0f;
  float c = (tid < nb) ? bcnt[tid] : 0.0f;
#pragma unroll
  for (int off = 32; off >= 1; off >>= 1) {
    s += __shfl_xor(s, off);
    c += __shfl_xor(c, off);
  }
  if (tid == 0) out[0] = s / fmaxf(c, 1.0f);
}

extern "C" void kernel_launch(void* const* d_in, const int* in_sizes, int n_in,
                              void* d_out, int out_size, void* d_ws, size_t ws_size,
                              hipStream_t stream) {
  const float* supp  = (const float*)d_in[0];   // (N, 256)
  const float* pred  = (const float*)d_in[1];   // (M, 256)
  const int*   suppT = (const int*)d_in[2];     // (N,)
  const int*   tgt   = (const int*)d_in[3];     // (M,)
  const int N = in_sizes[2];
  const int M = in_sizes[3];

  float* sn     = (float*)d_ws;                      // N
  float* denomP = sn + N;                            // NSLOT*M
  float* numerP = denomP + (size_t)NSLOT * M;        // NSLOT*M
  float* bsum   = numerP + (size_t)NSLOT * M;        // M/256
  float* bcnt   = bsum + 16;                         // M/256

  supp_prep_kernel<<<dim3(N / 8), dim3(256), 0, stream>>>(supp, sn, N);

  dim3 grid((M / GBM) * NSL);   // 1024 blocks; XCD = slice & 7
  kde_gemm_kernel<<<grid, dim3(256), 0, stream>>>(
      pred, supp, tgt, suppT, sn, denomP, numerP, M, N);

  kde_reduce_kernel<<<dim3(M / 256), dim3(256), 0, stream>>>(denomP, numerP, tgt, bsum, bcnt, M);
  kde_final_kernel<<<dim3(1), dim3(64), 0, stream>>>(bsum, bcnt, (float*)d_out, M / 256);
}

// Round 9
// 92.096 us; speedup vs baseline: 2.3125x; 2.0115x over previous
//
#include <hip/hip_runtime.h>
#include <hip/hip_bf16.h>

typedef __bf16 bf16x8 __attribute__((ext_vector_type(8)));
typedef float  f32x4  __attribute__((ext_vector_type(4)));
typedef short  short8 __attribute__((ext_vector_type(8)));
typedef unsigned int u32;

#define KDE_IGNORE (-100)
#define NSL  16       // N slices (2 per XCD)
#define GBM  64       // m rows per block
#define GBN  64       // n cols per n-tile
#define BK   128      // k per phase (2 phases over K=256)
#define GD   256
#define NSLOT (NSL * 2)

__device__ __forceinline__ f32x4 mfma16x16(bf16x8 a, bf16x8 b, f32x4 c) {
  return __builtin_amdgcn_mfma_f32_16x16x32_bf16(a, b, c, 0, 0, 0);
}

// async 16B/lane global->LDS (LDS dest = wave-uniform base + lane*16)
__device__ __forceinline__ void gload_lds16(const short* g, short* l) {
  __builtin_amdgcn_global_load_lds(
      (const __attribute__((address_space(1))) u32*)g,
      (__attribute__((address_space(3))) u32*)l, 16, 0, 0);
}

// convert 8 fp32 -> 8 bf16 (as bf16x8 for MFMA operands)
__device__ __forceinline__ bf16x8 cvt8b(const float* p) {
  float4 a = *reinterpret_cast<const float4*>(p);
  float4 b = *reinterpret_cast<const float4*>(p + 4);
  union { bf16x8 v; __bf16 h[8]; } u;
  u.h[0] = (__bf16)a.x; u.h[1] = (__bf16)a.y; u.h[2] = (__bf16)a.z; u.h[3] = (__bf16)a.w;
  u.h[4] = (__bf16)b.x; u.h[5] = (__bf16)b.y; u.h[6] = (__bf16)b.z; u.h[7] = (__bf16)b.w;
  return u.v;
}
__device__ __forceinline__ short8 cvt8s(const float* p) {
  union { bf16x8 b; short8 s; } u; u.b = cvt8b(p); return u.s;
}

// ---- Kernel 1: supp row norms (fp32 exact) + PRE-SWIZZLED bf16 copy.
// Row r, k-half h, logical chunk j (16B) stored at short offset
// r*256 + (h*16 + (j ^ (r & 15)))*8  -> staged half-tiles become LINEAR
// global_load_lds copies while readers keep the XOR-swizzled layout.
template<bool CONV>
__global__ void supp_prep_kernel(const float* __restrict__ supp, float* __restrict__ sn,
                                 short* __restrict__ suppB, int N) {
  int row = blockIdx.x * 8 + ((threadIdx.x >> 6) << 1) + ((threadIdx.x & 63) >> 5);
  int c = threadIdx.x & 31;                 // logical chunk 0..31
  const float* src = supp + (size_t)row * GD + c * 8;
  float4 a = *reinterpret_cast<const float4*>(src);
  float4 b = *reinterpret_cast<const float4*>(src + 4);
  if (CONV) {
    union { short8 v; __bf16 h[8]; } u;
    u.h[0] = (__bf16)a.x; u.h[1] = (__bf16)a.y; u.h[2] = (__bf16)a.z; u.h[3] = (__bf16)a.w;
    u.h[4] = (__bf16)b.x; u.h[5] = (__bf16)b.y; u.h[6] = (__bf16)b.z; u.h[7] = (__bf16)b.w;
    int h = c >> 4, j = c & 15;
    int pos = h * 16 + (j ^ (row & 15));
    *reinterpret_cast<short8*>(suppB + (size_t)row * GD + pos * 8) = u.v;
  }
  float s = a.x*a.x + a.y*a.y + a.z*a.z + a.w*a.w
          + b.x*b.x + b.y*b.y + b.z*b.z + b.w*b.w;
#pragma unroll
  for (int off = 16; off >= 1; off >>= 1) s += __shfl_xor(s, off, 32);
  if (c == 0) sn[row] = s;
}

// ---- Kernel 2: fused GEMM + exp + masked row-accumulate, atomic-free.
// 256 thr = 4 waves (2m x 2n); block tile 64m x 64n per n-tile, K phased 2x128.
// A (pred) full-K in registers (compile-time indexed); B half-tiles double-
// buffered in LDS via global_load_lds (PRE) or reg-staging (fallback).
// launch_bounds (256,3): VGPR cap ~170 >= demand ~125 -> NO SPILL.
template<bool PRE>
__global__ __launch_bounds__(256, 3)
void kde_gemm_kernel(const float* __restrict__ pred, const float* __restrict__ suppF,
                     const short* __restrict__ suppB,
                     const int* __restrict__ tgt, const int* __restrict__ suppT,
                     const float* __restrict__ sn,
                     float* __restrict__ denomP, float* __restrict__ numerP,
                     int M, int N) {
  __shared__ __align__(16) short Bs[2][GBN * BK];   // 2 x 16 KiB

  const int bid = blockIdx.x;
  const int mb  = bid >> 4;           // 0..M/64-1
  const int s   = bid & 15;           // slice; XCD = bid & 7
  const int m0  = mb * GBM;
  const int nslice = N >> 4;          // 1024
  const int nbase  = s * nslice;
  const int ntile  = nslice / GBN;    // 16 n-tiles (2 phases each)
  const int t    = threadIdx.x;
  const int lane = t & 63;
  const int wid  = t >> 6;            // 0..3
  const int wm   = (wid >> 1) * 32;
  const int wng  = wid & 1;
  const int wnl  = wng * 32;
  const int lr = lane >> 4, lc = lane & 15;

  // per-lane global offset (shorts) within a 4-row staging group
  const int gvoff = (lane >> 4) * GD + (lane & 15) * 8;

  // ---- A fragments: full K=256 in registers (bf16), converted once.
  bf16x8 af[2][8];
#pragma unroll
  for (int mt = 0; mt < 2; ++mt) {
    const float* base = pred + (size_t)(m0 + wm + mt * 16 + lc) * GD + lr * 8;
#pragma unroll
    for (int kk = 0; kk < 8; ++kk) af[mt][kk] = cvt8b(base + kk * 32);
  }
  int tmv[2][4];
#pragma unroll
  for (int mt = 0; mt < 2; ++mt)
#pragma unroll
    for (int rg = 0; rg < 4; ++rg)
      tmv[mt][rg] = tgt[m0 + wm + mt * 16 + lr * 4 + rg];

  float dac[2][4] = {}, nac[2][4] = {};

  const float SC  = 1.4426950408889634f / 128.0f;   // log2e/128 (for 2*dot)
  const float SCH = 1.4426950408889634f / 256.0f;   // log2e/256 (for sn)

  // ---- stage (tile 0, k-half 0) into Bs[0]
  if (PRE) {
#pragma unroll
    for (int i = 0; i < 4; ++i) {
      int rowbase = wid * 16 + i * 4;
      gload_lds16(suppB + (size_t)(nbase + rowbase) * GD + gvoff, &Bs[0][rowbase * BK]);
    }
  } else {
#pragma unroll
    for (int i = 0; i < 4; ++i) {
      int C = i * 256 + t; int row = C >> 4; int j = C & 15;
      short8 v = cvt8s(suppF + (size_t)(nbase + row) * GD + j * 8);
      *reinterpret_cast<short8*>(&Bs[0][row * BK + ((j ^ (row & 15)) << 3)]) = v;
    }
  }
  __syncthreads();

  f32x4 acc[2][2] = {};
  float snv[2]; int stv[2];
#pragma unroll
  for (int nt = 0; nt < 2; ++nt) {
    int j = nbase + wnl + nt * 16 + lc;
    snv[nt] = sn[j]; stv[nt] = suppT[j];
  }

  for (int it = 0; it < ntile; ++it) {
    const int n0 = nbase + it * GBN;
    const bool more = (it + 1 < ntile);

    // ======== phase 0: stage (it, kh=1) -> Bs[1]; compute k-half 0 from Bs[0]
    short8 sreg[4];
    if (PRE) {
#pragma unroll
      for (int i = 0; i < 4; ++i) {
        int rowbase = wid * 16 + i * 4;
        gload_lds16(suppB + (size_t)(n0 + rowbase) * GD + BK + gvoff, &Bs[1][rowbase * BK]);
      }
    } else {
#pragma unroll
      for (int i = 0; i < 4; ++i) {
        int C = i * 256 + t; int row = C >> 4; int j = C & 15;
        sreg[i] = cvt8s(suppF + (size_t)(n0 + row) * GD + BK + j * 8);
      }
    }
    __builtin_amdgcn_s_setprio(1);
#pragma unroll
    for (int ks = 0; ks < 4; ++ks) {
      bf16x8 bfr[2];
#pragma unroll
      for (int nt = 0; nt < 2; ++nt) {
        int r = wnl + nt * 16 + lc;
        int cs = (ks * 4 + lr) ^ (r & 15);
        bfr[nt] = *reinterpret_cast<const bf16x8*>(&Bs[0][r * BK + (cs << 3)]);
      }
#pragma unroll
      for (int mt = 0; mt < 2; ++mt)
#pragma unroll
        for (int nt = 0; nt < 2; ++nt)
          acc[mt][nt] = mfma16x16(af[mt][ks], bfr[nt], acc[mt][nt]);
    }
    __builtin_amdgcn_s_setprio(0);
    if (!PRE) {
#pragma unroll
      for (int i = 0; i < 4; ++i) {
        int C = i * 256 + t; int row = C >> 4; int j = C & 15;
        *reinterpret_cast<short8*>(&Bs[1][row * BK + ((j ^ (row & 15)) << 3)]) = sreg[i];
      }
    }
    __syncthreads();

    // ======== phase 1: stage (it+1, kh=0) -> Bs[0]; compute k-half 1 from Bs[1]
    if (more) {
      if (PRE) {
#pragma unroll
        for (int i = 0; i < 4; ++i) {
          int rowbase = wid * 16 + i * 4;
          gload_lds16(suppB + (size_t)(n0 + GBN + rowbase) * GD + gvoff, &Bs[0][rowbase * BK]);
        }
      } else {
#pragma unroll
        for (int i = 0; i < 4; ++i) {
          int C = i * 256 + t; int row = C >> 4; int j = C & 15;
          sreg[i] = cvt8s(suppF + (size_t)(n0 + GBN + row) * GD + j * 8);
        }
      }
    }
    __builtin_amdgcn_s_setprio(1);
#pragma unroll
    for (int ks = 0; ks < 4; ++ks) {
      bf16x8 bfr[2];
#pragma unroll
      for (int nt = 0; nt < 2; ++nt) {
        int r = wnl + nt * 16 + lc;
        int cs = (ks * 4 + lr) ^ (r & 15);
        bfr[nt] = *reinterpret_cast<const bf16x8*>(&Bs[1][r * BK + (cs << 3)]);
      }
#pragma unroll
      for (int mt = 0; mt < 2; ++mt)
#pragma unroll
        for (int nt = 0; nt < 2; ++nt)
          acc[mt][nt] = mfma16x16(af[mt][4 + ks], bfr[nt], acc[mt][nt]);
    }
    __builtin_amdgcn_s_setprio(0);
    if (!PRE && more) {
#pragma unroll
      for (int i = 0; i < 4; ++i) {
        int C = i * 256 + t; int row = C >> 4; int j = C & 15;
        *reinterpret_cast<short8*>(&Bs[0][row * BK + ((j ^ (row & 15)) << 3)]) = sreg[i];
      }
    }

    // ---- n-tile epilogue: e = 2^((2c - sn)*log2e/256); pn cancels in ratio
#pragma unroll
    for (int nt = 0; nt < 2; ++nt) {
      float sh = -snv[nt] * SCH;
#pragma unroll
      for (int mt = 0; mt < 2; ++mt)
#pragma unroll
        for (int rg = 0; rg < 4; ++rg) {
          float e = exp2f(fmaf(acc[mt][nt][rg], SC, sh));
          dac[mt][rg] += e;
          nac[mt][rg] += (stv[nt] == tmv[mt][rg]) ? e : 0.0f;
        }
    }
#pragma unroll
    for (int mt = 0; mt < 2; ++mt)
#pragma unroll
      for (int nt = 0; nt < 2; ++nt) acc[mt][nt] = f32x4{0.f, 0.f, 0.f, 0.f};
    if (more) {
      const int nn0 = n0 + GBN;
#pragma unroll
      for (int nt = 0; nt < 2; ++nt) {
        int j = nn0 + wnl + nt * 16 + lc;
        snv[nt] = sn[j]; stv[nt] = suppT[j];
      }
    }
    __syncthreads();
  }

  // reduce over the 16 lanes (lc) sharing each m, write slot partials
#pragma unroll
  for (int off = 1; off < 16; off <<= 1) {
#pragma unroll
    for (int mt = 0; mt < 2; ++mt)
#pragma unroll
      for (int rg = 0; rg < 4; ++rg) {
        dac[mt][rg] += __shfl_xor(dac[mt][rg], off);
        nac[mt][rg] += __shfl_xor(nac[mt][rg], off);
      }
  }
  if (lc == 0) {
    const int slot = s * 2 + wng;           // 32 slots per m
#pragma unroll
    for (int mt = 0; mt < 2; ++mt)
#pragma unroll
      for (int rg = 0; rg < 4; ++rg) {
        int m = m0 + wm + mt * 16 + lr * 4 + rg;
        denomP[(size_t)slot * M + m] = dac[mt][rg];
        numerP[(size_t)slot * M + m] = nac[mt][rg];
      }
  }
}

// ---- Kernel 3: per-m sum over 32 slots -> nll, per-block partial sums
__global__ void kde_reduce_kernel(const float* __restrict__ denomP, const float* __restrict__ numerP,
                                  const int* __restrict__ tgt,
                                  float* __restrict__ bsum, float* __restrict__ bcnt, int M) {
  __shared__ float sS[4], sC[4];
  int m = blockIdx.x * 256 + threadIdx.x;
  float den = 0.0f, num = 0.0f;
#pragma unroll
  for (int sl = 0; sl < NSLOT; ++sl) {
    den += denomP[(size_t)sl * M + m];
    num += numerP[(size_t)sl * M + m];
  }
  int tg = tgt[m];
  bool valid = (tg != KDE_IGNORE);
  float p = fmaxf(num / fmaxf(den, 1e-10f), 1e-10f);
  float nll = valid ? -logf(p) : 0.0f;
  float cnt = valid ? 1.0f : 0.0f;
#pragma unroll
  for (int off = 32; off >= 1; off >>= 1) {
    nll += __shfl_xor(nll, off);
    cnt += __shfl_xor(cnt, off);
  }
  int wid = threadIdx.x >> 6, lane = threadIdx.x & 63;
  if (lane == 0) { sS[wid] = nll; sC[wid] = cnt; }
  __syncthreads();
  if (threadIdx.x == 0) {
    bsum[blockIdx.x] = sS[0] + sS[1] + sS[2] + sS[3];
    bcnt[blockIdx.x] = sC[0] + sC[1] + sC[2] + sC[3];
  }
}

__global__ void kde_final_kernel(const float* __restrict__ bsum, const float* __restrict__ bcnt,
                                 float* __restrict__ out, int nb) {
  int tid = threadIdx.x;
  float s = (tid < nb) ? bsum[tid] : 0.0f;
  float c = (tid < nb) ? bcnt[tid] : 0.0f;
#pragma unroll
  for (int off = 32; off >= 1; off >>= 1) {
    s += __shfl_xor(s, off);
    c += __shfl_xor(c, off);
  }
  if (tid == 0) out[0] = s / fmaxf(c, 1.0f);
}

extern "C" void kernel_launch(void* const* d_in, const int* in_sizes, int n_in,
                              void* d_out, int out_size, void* d_ws, size_t ws_size,
                              hipStream_t stream) {
  const float* supp  = (const float*)d_in[0];   // (N, 256)
  const float* pred  = (const float*)d_in[1];   // (M, 256)
  const int*   suppT = (const int*)d_in[2];     // (N,)
  const int*   tgt   = (const int*)d_in[3];     // (M,)
  const int N = in_sizes[2];
  const int M = in_sizes[3];

  float* sn     = (float*)d_ws;                      // N
  float* denomP = sn + N;                            // NSLOT*M
  float* numerP = denomP + (size_t)NSLOT * M;        // NSLOT*M
  float* bsum   = numerP + (size_t)NSLOT * M;        // M/256
  float* bcnt   = bsum + 16;                         // M/256
  short* suppB  = (short*)(bcnt + 16);               // N*256 bf16 (pre-swizzled)

  size_t small = sizeof(float) * ((size_t)N + 2 * (size_t)NSLOT * M + 32);
  bool pre = ws_size >= small + sizeof(short) * (size_t)N * GD;

  if (pre) supp_prep_kernel<true ><<<dim3(N / 8), dim3(256), 0, stream>>>(supp, sn, suppB, N);
  else     supp_prep_kernel<false><<<dim3(N / 8), dim3(256), 0, stream>>>(supp, sn, nullptr, N);

  dim3 grid((M / GBM) * NSL);   // 1024 blocks; XCD = bid & 7
  if (pre) kde_gemm_kernel<true ><<<grid, dim3(256), 0, stream>>>(
      pred, supp, suppB, tgt, suppT, sn, denomP, numerP, M, N);
  else     kde_gemm_kernel<false><<<grid, dim3(256), 0, stream>>>(
      pred, supp, suppB, tgt, suppT, sn, denomP, numerP, M, N);

  kde_reduce_kernel<<<dim3(M / 256), dim3(256), 0, stream>>>(denomP, numerP, tgt, bsum, bcnt, M);
  kde_final_kernel<<<dim3(1), dim3(64), 0, stream>>>(bsum, bcnt, (float*)d_out, M / 256);
}